// Round 15
// baseline (81.586 us; speedup 1.0000x reference)
//
#include <hip/hip_runtime.h>
#include <stdint.h>

#define DIMC 512
#define INNER 512
#define NTOK 8192     // F*H*W = 8*32*32
#define NSEQ 8193     // +bos
#define MPAD1 8448    // 33*256
#define QKV_COLS 1536

#define WTILES 256                            // 192 wqkv + 64 wout transpose tiles
#define CONV_XT (MPAD1 * DIMC / 4)            // 1,081,344 x-vec4 elements
#define XBLKS   (CONV_XT / 256)               // 4224 blocks for x conversion

typedef __attribute__((ext_vector_type(8))) short bf16x8;
typedef __attribute__((ext_vector_type(4))) float f32x4;
typedef __attribute__((ext_vector_type(8))) unsigned short u16x8;

__device__ __forceinline__ float bf2f(unsigned short u) {
  return __uint_as_float(((unsigned int)u) << 16);
}
__device__ __forceinline__ unsigned short f2bf(float f) {
  unsigned int x = __float_as_uint(f);
  unsigned int lsb = (x >> 16) & 1u;
  x += 0x7fffu + lsb;           // round-to-nearest-even
  return (unsigned short)(x >> 16);
}

__device__ __forceinline__ void gload_lds16(const unsigned short* g, unsigned short* l) {
  __builtin_amdgcn_global_load_lds(
      (const __attribute__((address_space(1))) void*)g,
      (__attribute__((address_space(3))) void*)l, 16, 0, 0);
}

// ---------- fused conversions ----------
// blocks [0, WTILES): weight transpose via 64x64 LDS tile (coalesced r/w)
// blocks [WTILES, +XBLKS): x -> bf16 padded (coalesced both sides)
__global__ void k_conv(const float* __restrict__ x, const float* __restrict__ wq,
                       const float* __restrict__ wkv, const float* __restrict__ wout,
                       unsigned short* __restrict__ xb, unsigned short* __restrict__ wqkvT,
                       unsigned short* __restrict__ woutT) {
  __shared__ float tl[64][65];
  const int bid = (int)blockIdx.x;
  const int tid = (int)threadIdx.x;
  if (bid >= WTILES) {
    const int idx = ((bid - WTILES) * 256 + tid) * 4;
    const int row = idx / DIMC;
    ushort4 o;
    if (row < NSEQ) {
      const float4 v = *(const float4*)(x + idx);
      o.x = f2bf(v.x); o.y = f2bf(v.y); o.z = f2bf(v.z); o.w = f2bf(v.w);
    } else {
      o.x = 0; o.y = 0; o.z = 0; o.w = 0;
    }
    *(ushort4*)(xb + idx) = o;
    return;
  }
  const bool is_qkv = bid < 192;
  const int t2 = is_qkv ? bid : bid - 192;
  const int k0 = (t2 & 7) * 64;
  const int c0 = (t2 >> 3) * 64;
  const int cc = tid & 63;
  const int rq = tid >> 6;          // 0..3
#pragma unroll
  for (int p = 0; p < 16; ++p) {
    const int r = p * 4 + rq;       // 0..63
    float v;
    if (is_qkv) {
      v = (c0 + cc < INNER) ? wq[(k0 + r) * INNER + c0 + cc] * 0.125f
                            : wkv[(k0 + r) * (2 * INNER) + c0 + cc - INNER];
    } else {
      v = wout[(k0 + r) * DIMC + c0 + cc];
    }
    tl[r][cc] = v;
  }
  __syncthreads();
  const int kk = tid & 63;
#pragma unroll
  for (int p = 0; p < 16; ++p) {
    const int c = p * 4 + rq;       // 0..63
    const unsigned short ov = f2bf(tl[kk][c]);
    if (is_qkv) wqkvT[(size_t)(c0 + c) * DIMC + k0 + kk] = ov;
    else        woutT[(size_t)(c0 + c) * DIMC + k0 + kk] = ov;
  }
}

// ---------- GEMM: C[M x N] = A[M x 512] * B[512 x N], BT given N x 512 ----------
// 2-barrier BK=64 structure (proven). Pure PARAMETER generalization: BM=256 ->
// 8 waves in 4m x 2n arrangement, wave tile 64 x (BN/2); BM=128 -> 4 waves,
// wave tile 32 x BN. 1D grid, tn-fastest + bijective XCD swizzle (m204).
template <int BM, int BN, int TN, int LDC, bool OUT_BF16>
__global__ __launch_bounds__((BM == 256) ? 512 : 256)
void k_gemm(const unsigned short* __restrict__ A,
            const unsigned short* __restrict__ BT,
            void* __restrict__ C,
            const float* __restrict__ bias,
            int Mreal) {
  constexpr int NW = (BM == 256) ? 8 : 4;      // waves per block
  constexpr int WME = BM / 4;                  // wave M extent (64 or 32)
  constexpr int WNE = (BM == 256) ? BN / 2 : BN;  // wave N extent
  constexpr int MF = WME / 16;                 // m-fragments per wave
  constexpr int NF = WNE / 16;                 // n-fragments per wave
  constexpr int ISS_A = BM / NW / 8;           // A staging issues per wave
  constexpr int ISS_B = BN / NW / 8;           // B staging issues per wave
  __shared__ unsigned short As[BM * 64];
  __shared__ unsigned short Bs[BN * 64];

  int flat;
  {
    const int nwg = (int)gridDim.x;
    const int q = nwg >> 3, r = nwg & 7;
    const int xcd = (int)blockIdx.x & 7, idx = (int)blockIdx.x >> 3;
    flat = (xcd < r ? xcd * (q + 1) : r * (q + 1) + (xcd - r) * q) + idx;
  }
  const int tm = flat / TN;
  const int tn = flat % TN;

  const int tid = (int)threadIdx.x;
  const int wave = tid >> 6;
  const int lane = tid & 63;
  int wm, wn;
  if constexpr (BM == 256) { wm = (wave >> 1) * WME; wn = (wave & 1) * WNE; }
  else                     { wm = wave * WME;        wn = 0; }

  f32x4 acc[MF][NF];
#pragma unroll
  for (int m = 0; m < MF; ++m)
#pragma unroll
    for (int n = 0; n < NF; ++n) {
      acc[m][n][0] = 0.f; acc[m][n][1] = 0.f; acc[m][n][2] = 0.f; acc[m][n][3] = 0.f;
    }

  const size_t a_base = (size_t)tm * BM * DIMC;
  const size_t b_base = (size_t)tn * BN * DIMC;
  const int lrow = lane >> 3;        // 0..7
  const int lk = (lane & 7) * 8;     // 0..56 shorts (16B units)

  for (int k0 = 0; k0 < DIMC; k0 += 64) {
    __syncthreads();   // previous tile fully consumed
#pragma unroll
    for (int c = 0; c < ISS_A; ++c) {
      const int rA = wave * (BM / NW) + c * 8;     // wave-uniform
      gload_lds16(A + a_base + (size_t)(rA + lrow) * DIMC + k0 + lk, &As[rA * 64]);
    }
#pragma unroll
    for (int c = 0; c < ISS_B; ++c) {
      const int rB = wave * (BN / NW) + c * 8;     // wave-uniform
      gload_lds16(BT + b_base + (size_t)(rB + lrow) * DIMC + k0 + lk, &Bs[rB * 64]);
    }
    __syncthreads();   // data ready (compiler drains vmcnt before barrier)

    const int fr = lane & 15;
    const int kg = (lane >> 4) * 8;
#pragma unroll
    for (int kk = 0; kk < 2; ++kk) {               // two K=32 sub-phases
      bf16x8 af[MF], bfr[NF];
#pragma unroll
      for (int m = 0; m < MF; ++m)
        af[m] = *(const bf16x8*)&As[(wm + m * 16 + fr) * 64 + kk * 32 + kg];
#pragma unroll
      for (int n = 0; n < NF; ++n)
        bfr[n] = *(const bf16x8*)&Bs[(wn + n * 16 + fr) * 64 + kk * 32 + kg];
#pragma unroll
      for (int m = 0; m < MF; ++m)
#pragma unroll
        for (int n = 0; n < NF; ++n)
          acc[m][n] = __builtin_amdgcn_mfma_f32_16x16x32_bf16(af[m], bfr[n], acc[m][n], 0, 0, 0);
    }
  }

  // epilogue: D col = lane&15, row = (lane>>4)*4 + reg   [m89/m91 verified]
  const int fr = lane & 15;
  const int rg = (lane >> 4) * 4;
#pragma unroll
  for (int m = 0; m < MF; ++m) {
#pragma unroll
    for (int r = 0; r < 4; ++r) {
      const int row = tm * BM + wm + m * 16 + rg + r;
      if (row < Mreal) {
#pragma unroll
        for (int n = 0; n < NF; ++n) {
          const int col = tn * BN + wn + n * 16 + fr;
          const float v = acc[m][n][r];
          if constexpr (OUT_BF16) {
            ((unsigned short*)C)[(size_t)row * LDC + col] = f2bf(v);
          } else {
            ((float*)C)[(size_t)row * LDC + col] = v + bias[col];
          }
        }
      }
    }
  }
}

// ---------- attention: one WAVE per token; 2x2 (y,x) token tile per block ----------
__global__ __launch_bounds__(256)
void k_attn3(const unsigned short* __restrict__ qkv, const float* __restrict__ w_th,
             unsigned short* __restrict__ Ob) {
  const int bid = (int)blockIdx.x;
  const int t = (int)threadIdx.x;
  if (bid == NTOK / 4) {            // extra block: BOS output row O[0] = v_bos
    *(unsigned int*)(Ob + 2 * t) = *(const unsigned int*)(qkv + 2 * INNER + 2 * t);
    return;
  }
  const int blk = ((bid & 7) << 8) | (bid >> 3);   // XCD swizzle: 2048 = 8*256
  const int w = t >> 6;
  const int l = t & 63;
  // block covers a 2x2 (y,x) tile: f = blk>>8, ty = (blk>>4)&15, tx = blk&15
  const int i = (blk >> 8 << 10) | ((((blk >> 4) & 15) * 2 + (w >> 1)) << 5)
              | ((blk & 15) * 2 + (w & 1));        // token 0..8191
  const int e = l & 7;                              // element-group within head
  const int gbase = l & 56;                         // h*8

  // lane l (<27) holds packed neighbor: qkv row (tok+1) if valid else -1
  int my_pack = -1;
  {
    const int f = i >> 10, rr = i & 1023, y = rr >> 5, xx = rr & 31;
    const int a = l / 9, rem = l % 9, bb = rem / 3, cc = rem % 3;
    const int sf = f + a - 1, sy = y + bb - 1, sx = xx + cc - 1;
    if (l < 27 && (unsigned)sf < 8u && (unsigned)sy < 32u && (unsigned)sx < 32u) {
      const int tk = (sf << 10) | (sy << 5) | sx;
      if (tk <= i) my_pack = tk + 1;               // causal
    }
  }
  const unsigned long long mask0 = __ballot(my_pack >= 0);   // wave-uniform
  const int nval = __popcll(mask0);                           // >= 1 always (self)

  // q fragment: head h = l>>3, dims e*8..e*8+7  (scale folded into w_q)
  float qf[8];
  {
    const u16x8 q8 = *(const u16x8*)(qkv + (size_t)(i + 1) * QKV_COLS + l * 8);
#pragma unroll
    for (int u = 0; u < 8; ++u) qf[u] = bf2f(q8[u]);
  }

  // ---- sim: s[p] = sim[h][8p+e]; mask-walk unrolled x2, independent chains ----
  float s[4] = {-1e30f, -1e30f, -1e30f, -1e30f};
  const unsigned short* kbase = qkv + INNER + l * 8;
  {  // j = 0: BOS, row 0, never masked
    const u16x8 k8 = *(const u16x8*)kbase;
    float p = 0.f;
#pragma unroll
    for (int u = 0; u < 8; ++u) p = fmaf(qf[u], bf2f(k8[u]), p);
    p += __shfl_xor(p, 1); p += __shfl_xor(p, 2); p += __shfl_xor(p, 4);
    if (e == 0) s[0] = p;
  }
  __builtin_amdgcn_s_setprio(1);
  {
    unsigned long long mask = mask0;
    for (int it = 0; it < nval; it += 2) {
      const int l0 = (int)__builtin_ctzll(mask);
      mask &= mask - 1;
      const bool has1 = (it + 1) < nval;
      const int l1 = mask ? (int)__builtin_ctzll(mask) : 0;
      mask &= mask - 1;                             // 0 stays 0
      const int pk0 = __shfl(my_pack, l0);          // valid by construction
      const int pk1r = __shfl(my_pack, l1);
      const int pk1 = has1 ? pk1r : 0;              // dummy row 0 on tail
      const u16x8 ka = *(const u16x8*)(kbase + (size_t)pk0 * QKV_COLS);
      const u16x8 kb = *(const u16x8*)(kbase + (size_t)pk1 * QKV_COLS);
      float p0 = 0.f, p1 = 0.f;
#pragma unroll
      for (int u = 0; u < 8; ++u) {
        p0 = fmaf(qf[u], bf2f(ka[u]), p0);
        p1 = fmaf(qf[u], bf2f(kb[u]), p1);
      }
      p0 += __shfl_xor(p0, 1); p1 += __shfl_xor(p1, 1);
      p0 += __shfl_xor(p0, 2); p1 += __shfl_xor(p1, 2);
      p0 += __shfl_xor(p0, 4); p1 += __shfl_xor(p1, 4);
      {
        const int js = l0 + 1;                      // wave-uniform
        const bool mine = (e == (js & 7));
        const int pp = js >> 3;
        s[0] = (mine && pp == 0) ? p0 : s[0];
        s[1] = (mine && pp == 1) ? p0 : s[1];
        s[2] = (mine && pp == 2) ? p0 : s[2];
        s[3] = (mine && pp == 3) ? p0 : s[3];
      }
      {
        const int js = l1 + 1;
        const bool mine = has1 && (e == (js & 7));
        const int pp = js >> 3;
        s[0] = (mine && pp == 0) ? p1 : s[0];
        s[1] = (mine && pp == 1) ? p1 : s[1];
        s[2] = (mine && pp == 2) ? p1 : s[2];
        s[3] = (mine && pp == 3) ? p1 : s[3];
      }
    }
  }

  // ---- softmax over 28 entries spread across 8 lanes x 4 regs ----
  float mx = fmaxf(fmaxf(s[0], s[1]), fmaxf(s[2], s[3]));
  mx = fmaxf(mx, __shfl_xor(mx, 1));
  mx = fmaxf(mx, __shfl_xor(mx, 2));
  mx = fmaxf(mx, __shfl_xor(mx, 4));
  float a4[4]; float sum = 0.f;
#pragma unroll
  for (int p = 0; p < 4; ++p) { a4[p] = __expf(s[p] - mx); sum += a4[p]; }
  sum += __shfl_xor(sum, 1); sum += __shfl_xor(sum, 2); sum += __shfl_xor(sum, 4);
  const float inv = 1.0f / sum;
#pragma unroll
  for (int p = 0; p < 4; ++p) a4[p] *= inv;

  // ---- talking heads: m4[p] = mixed[h][8p+e] = sum_h2 wth[h][h2]*attn[h2][8p+e] ----
  float wth[8];
  {
    const float4 w0 = *(const float4*)(w_th + gbase);
    const float4 w1 = *(const float4*)(w_th + gbase + 4);
    wth[0] = w0.x; wth[1] = w0.y; wth[2] = w0.z; wth[3] = w0.w;
    wth[4] = w1.x; wth[5] = w1.y; wth[6] = w1.z; wth[7] = w1.w;
  }
  float m4[4];
#pragma unroll
  for (int p = 0; p < 4; ++p) {
    float acc = 0.f;
#pragma unroll
    for (int h2 = 0; h2 < 8; ++h2)
      acc = fmaf(wth[h2], __shfl(a4[p], (h2 << 3) | e), acc);
    m4[p] = acc;
  }

  // ---- PV: acc8/accb dual accumulators; mask-walk unrolled x2 ----
  float acc8[8] = {0.f, 0.f, 0.f, 0.f, 0.f, 0.f, 0.f, 0.f};
  float accb[8] = {0.f, 0.f, 0.f, 0.f, 0.f, 0.f, 0.f, 0.f};
  const unsigned short* vbase = qkv + 2 * INNER + l * 8;
  {  // BOS
    const float mv = __shfl(m4[0], gbase);
    const u16x8 v8 = *(const u16x8*)vbase;
#pragma unroll
    for (int u = 0; u < 8; ++u) acc8[u] = fmaf(mv, bf2f(v8[u]), acc8[u]);
  }
  {
    unsigned long long mask = mask0;
    for (int it = 0; it < nval; it += 2) {
      const int l0 = (int)__builtin_ctzll(mask);
      mask &= mask - 1;
      const bool has1 = (it + 1) < nval;
      const int l1 = mask ? (int)__builtin_ctzll(mask) : 0;
      mask &= mask - 1;
      const int pk0 = __shfl(my_pack, l0);
      const int pk1r = __shfl(my_pack, l1);
      const int pk1 = has1 ? pk1r : 0;
      const u16x8 va = *(const u16x8*)(vbase + (size_t)pk0 * QKV_COLS);
      const u16x8 vb = *(const u16x8*)(vbase + (size_t)pk1 * QKV_COLS);
      const int js0 = l0 + 1;
      const int pp0 = js0 >> 3;
      const float ms0 = pp0 == 0 ? m4[0] : pp0 == 1 ? m4[1] : pp0 == 2 ? m4[2] : m4[3];
      const float mv0 = __shfl(ms0, gbase | (js0 & 7));
      const int js1 = l1 + 1;
      const int pp1 = js1 >> 3;
      const float ms1 = pp1 == 0 ? m4[0] : pp1 == 1 ? m4[1] : pp1 == 2 ? m4[2] : m4[3];
      const float mv1r = __shfl(ms1, gbase | (js1 & 7));
      const float mv1 = has1 ? mv1r : 0.f;          // tail contributes exactly 0
#pragma unroll
      for (int u = 0; u < 8; ++u) {
        acc8[u] = fmaf(mv0, bf2f(va[u]), acc8[u]);
        accb[u] = fmaf(mv1, bf2f(vb[u]), accb[u]);
      }
    }
  }
  __builtin_amdgcn_s_setprio(0);

  // store 16B coalesced
  u16x8 o;
#pragma unroll
  for (int u = 0; u < 8; ++u) o[u] = f2bf(acc8[u] + accb[u]);
  *(u16x8*)(Ob + (size_t)(i + 1) * INNER + l * 8) = o;
}

extern "C" void kernel_launch(void* const* d_in, const int* in_sizes, int n_in,
                              void* d_out, int out_size, void* d_ws, size_t ws_size,
                              hipStream_t stream) {
  (void)in_sizes; (void)n_in; (void)out_size; (void)ws_size;
  const float* x     = (const float*)d_in[0];
  const float* w_q   = (const float*)d_in[1];
  const float* w_kv  = (const float*)d_in[2];
  const float* w_th  = (const float*)d_in[3];
  const float* w_out = (const float*)d_in[4];
  const float* b_out = (const float*)d_in[5];
  float* out = (float*)d_out;

  char* ws = (char*)d_ws;
  unsigned short* xb    = (unsigned short*)ws;                // 8448*512 bf16 (reused as Ob)
  unsigned short* wqkvT = (unsigned short*)(ws + 8650752);    // 1536*512 bf16
  unsigned short* woutT = (unsigned short*)(ws + 10223616);   // 512*512 bf16
  unsigned short* qkvb  = (unsigned short*)(ws + 10747904);   // 8193*1536 bf16

  // 1) fused conversions (weight tiles first, then x)
  k_conv<<<WTILES + XBLKS, 256, 0, stream>>>(x, w_q, w_kv, w_out, xb, wqkvT, woutT);
  // 2) qkv = xb @ [w_q*0.125 | w_kv]   (198 blocks, 256x256 tiles, <=1 block/CU)
  k_gemm<256, 256, QKV_COLS / 256, QKV_COLS, true>
      <<<(MPAD1 / 256) * (QKV_COLS / 256), 512, 0, stream>>>(xb, wqkvT, qkvb, nullptr, NSEQ);
  // 3) sparse attention: one wave per token, 2x2 tile per block (+1 block BOS row)
  k_attn3<<<NTOK / 4 + 1, 256, 0, stream>>>(qkvb, w_th, xb);
  // 4) out = Ob @ w_out + b_out   (132 blocks, 256x128 tiles, <=1 block/CU)
  k_gemm<256, 128, DIMC / 128, DIMC, false>
      <<<(MPAD1 / 256) * (DIMC / 128), 512, 0, stream>>>(xb, woutT, out, b_out, NSEQ);
}

// Round 16
// 70.283 us; speedup vs baseline: 1.1608x; 1.1608x over previous
//
#include <hip/hip_runtime.h>
#include <stdint.h>

#define DIMC 512
#define INNER 512
#define NTOK 8192     // F*H*W = 8*32*32
#define NSEQ 8193     // +bos
#define MPAD1 8448    // 33*256  (GEMM1 M-tiles)
#define QKV_COLS 1536

#define CONV_XT   (MPAD1 * DIMC / 4)
#define CONV_WQKV (QKV_COLS * DIMC)
#define CONV_WOUT (INNER * DIMC)
#define CONV_TOT  (CONV_XT + CONV_WQKV + CONV_WOUT)   // 2,129,920 = 8320*256

typedef __attribute__((ext_vector_type(8))) short bf16x8;
typedef __attribute__((ext_vector_type(4))) float f32x4;
typedef __attribute__((ext_vector_type(8))) unsigned short u16x8;

__device__ __forceinline__ float bf2f(unsigned short u) {
  return __uint_as_float(((unsigned int)u) << 16);
}
__device__ __forceinline__ unsigned short f2bf(float f) {
  unsigned int x = __float_as_uint(f);
  unsigned int lsb = (x >> 16) & 1u;
  x += 0x7fffu + lsb;           // round-to-nearest-even
  return (unsigned short)(x >> 16);
}

__device__ __forceinline__ void gload_lds16(const unsigned short* g, unsigned short* l) {
  __builtin_amdgcn_global_load_lds(
      (const __attribute__((address_space(1))) void*)g,
      (__attribute__((address_space(3))) void*)l, 16, 0, 0);
}

// ---------- fused conversions: x -> bf16 (padded to 8448), weights -> bf16 transposed ----------
__global__ void k_conv(const float* __restrict__ x, const float* __restrict__ wq,
                       const float* __restrict__ wkv, const float* __restrict__ wout,
                       unsigned short* __restrict__ xb, unsigned short* __restrict__ wqkvT,
                       unsigned short* __restrict__ woutT) {
  const int gid = blockIdx.x * 256 + threadIdx.x;
  if (gid < CONV_XT) {
    const int idx = gid * 4;
    const int row = idx / DIMC;
    ushort4 o;
    if (row < NSEQ) {
      const float4 v = *(const float4*)(x + idx);
      o.x = f2bf(v.x); o.y = f2bf(v.y); o.z = f2bf(v.z); o.w = f2bf(v.w);
    } else {
      o.x = 0; o.y = 0; o.z = 0; o.w = 0;
    }
    *(ushort4*)(xb + idx) = o;
  } else if (gid < CONV_XT + CONV_WQKV) {
    const int idx = gid - CONV_XT;
    const int c = idx / DIMC, k = idx % DIMC;
    const float v = (c < INNER) ? wq[k * INNER + c] * 0.125f   // fold q scale d^-0.5
                                : wkv[k * (2 * INNER) + (c - INNER)];
    wqkvT[idx] = f2bf(v);
  } else {
    const int idx = gid - CONV_XT - CONV_WQKV;
    const int c = idx / DIMC, k = idx % DIMC;
    woutT[idx] = f2bf(wout[k * DIMC + c]);
  }
}

// ---------- GEMM: C[M x N] = A[M x 512] * B[512 x N], BT given N x 512 ----------
// BM x BN tile, BK=64, 2-barrier structure. 1D grid, tn-fastest + bijective XCD
// swizzle (m204). BM=256/BN=128: 8 waves (4m x 2n, 64x64 each). BM=128/BN=64:
// 4 waves (32x64 each).
template <int BM, int BN, int TN, int LDC, bool OUT_BF16>
__global__ __launch_bounds__((BM == 256) ? 512 : 256)
void k_gemm(const unsigned short* __restrict__ A,
            const unsigned short* __restrict__ BT,
            void* __restrict__ C,
            const float* __restrict__ bias,
            int Mreal) {
  constexpr int NW = (BM == 256) ? 8 : 4;      // waves per block
  constexpr int MF = (BM == 256) ? 4 : 2;      // 16-row m-fragments per wave
  constexpr int ISS_A = BM / NW / 8;           // A staging issues per wave
  constexpr int ISS_B = BN / NW / 8;           // B staging issues per wave
  __shared__ unsigned short As[BM * 64];
  __shared__ unsigned short Bs[BN * 64];

  int flat;
  {
    const int nwg = (int)gridDim.x;
    const int q = nwg >> 3, r = nwg & 7;
    const int xcd = (int)blockIdx.x & 7, idx = (int)blockIdx.x >> 3;
    flat = (xcd < r ? xcd * (q + 1) : r * (q + 1) + (xcd - r) * q) + idx;
  }
  const int tm = flat / TN;
  const int tn = flat % TN;

  const int tid = (int)threadIdx.x;
  const int wave = tid >> 6;
  const int lane = tid & 63;
  int wm, wn;
  if constexpr (BM == 256) { wm = (wave >> 1) * 64; wn = (wave & 1) * 64; }
  else                     { wm = wave * 32;        wn = 0; }

  f32x4 acc[MF][4];
#pragma unroll
  for (int m = 0; m < MF; ++m)
#pragma unroll
    for (int n = 0; n < 4; ++n) {
      acc[m][n][0] = 0.f; acc[m][n][1] = 0.f; acc[m][n][2] = 0.f; acc[m][n][3] = 0.f;
    }

  const size_t a_base = (size_t)tm * BM * DIMC;
  const size_t b_base = (size_t)tn * BN * DIMC;
  const int lrow = lane >> 3;        // 0..7
  const int lk = (lane & 7) * 8;     // 0..56 shorts (16B units)

  for (int k0 = 0; k0 < DIMC; k0 += 64) {
    __syncthreads();   // previous tile fully consumed
#pragma unroll
    for (int c = 0; c < ISS_A; ++c) {
      const int rA = wave * (BM / NW) + c * 8;     // wave-uniform
      gload_lds16(A + a_base + (size_t)(rA + lrow) * DIMC + k0 + lk, &As[rA * 64]);
    }
#pragma unroll
    for (int c = 0; c < ISS_B; ++c) {
      const int rB = wave * (BN / NW) + c * 8;     // wave-uniform
      gload_lds16(BT + b_base + (size_t)(rB + lrow) * DIMC + k0 + lk, &Bs[rB * 64]);
    }
    __syncthreads();   // data ready (compiler drains vmcnt before barrier)

    const int fr = lane & 15;
    const int kg = (lane >> 4) * 8;
#pragma unroll
    for (int kk = 0; kk < 2; ++kk) {               // two K=32 sub-phases
      bf16x8 af[MF], bfr[4];
#pragma unroll
      for (int m = 0; m < MF; ++m)
        af[m] = *(const bf16x8*)&As[(wm + m * 16 + fr) * 64 + kk * 32 + kg];
#pragma unroll
      for (int n = 0; n < 4; ++n)
        bfr[n] = *(const bf16x8*)&Bs[(wn + n * 16 + fr) * 64 + kk * 32 + kg];
#pragma unroll
      for (int m = 0; m < MF; ++m)
#pragma unroll
        for (int n = 0; n < 4; ++n)
          acc[m][n] = __builtin_amdgcn_mfma_f32_16x16x32_bf16(af[m], bfr[n], acc[m][n], 0, 0, 0);
    }
  }

  // epilogue: D col = lane&15, row = (lane>>4)*4 + reg   [m89/m91 verified]
  const int fr = lane & 15;
  const int rg = (lane >> 4) * 4;
#pragma unroll
  for (int m = 0; m < MF; ++m) {
#pragma unroll
    for (int r = 0; r < 4; ++r) {
      const int row = tm * BM + wm + m * 16 + rg + r;
      if (row < Mreal) {
#pragma unroll
        for (int n = 0; n < 4; ++n) {
          const int col = tn * BN + wn + n * 16 + fr;
          const float v = acc[m][n][r];
          if constexpr (OUT_BF16) {
            ((unsigned short*)C)[(size_t)row * LDC + col] = f2bf(v);
          } else {
            ((float*)C)[(size_t)row * LDC + col] = v + bias[col];
          }
        }
      }
    }
  }
}

// ---------- attention: one WAVE per token; 2x2 (y,x) token tile per block ----------
__global__ __launch_bounds__(256)
void k_attn3(const unsigned short* __restrict__ qkv, const float* __restrict__ w_th,
             unsigned short* __restrict__ Ob) {
  const int bid = (int)blockIdx.x;
  const int t = (int)threadIdx.x;
  if (bid == NTOK / 4) {            // extra block: BOS output row O[0] = v_bos
    *(unsigned int*)(Ob + 2 * t) = *(const unsigned int*)(qkv + 2 * INNER + 2 * t);
    return;
  }
  const int blk = ((bid & 7) << 8) | (bid >> 3);   // XCD swizzle: 2048 = 8*256
  const int w = t >> 6;
  const int l = t & 63;
  // block covers a 2x2 (y,x) tile: f = blk>>8, ty = (blk>>4)&15, tx = blk&15
  const int i = (blk >> 8 << 10) | ((((blk >> 4) & 15) * 2 + (w >> 1)) << 5)
              | ((blk & 15) * 2 + (w & 1));        // token 0..8191
  const int e = l & 7;                              // element-group within head
  const int gbase = l & 56;                         // h*8

  // lane l (<27) holds packed neighbor: qkv row (tok+1) if valid else -1
  int my_pack = -1;
  {
    const int f = i >> 10, rr = i & 1023, y = rr >> 5, xx = rr & 31;
    const int a = l / 9, rem = l % 9, bb = rem / 3, cc = rem % 3;
    const int sf = f + a - 1, sy = y + bb - 1, sx = xx + cc - 1;
    if (l < 27 && (unsigned)sf < 8u && (unsigned)sy < 32u && (unsigned)sx < 32u) {
      const int tk = (sf << 10) | (sy << 5) | sx;
      if (tk <= i) my_pack = tk + 1;               // causal
    }
  }
  const unsigned long long mask0 = __ballot(my_pack >= 0);   // wave-uniform
  const int nval = __popcll(mask0);                           // >= 1 always (self)

  // q fragment: head h = l>>3, dims e*8..e*8+7  (scale folded into w_q)
  float qf[8];
  {
    const u16x8 q8 = *(const u16x8*)(qkv + (size_t)(i + 1) * QKV_COLS + l * 8);
#pragma unroll
    for (int u = 0; u < 8; ++u) qf[u] = bf2f(q8[u]);
  }

  // ---- sim: s[p] = sim[h][8p+e]; mask-walk unrolled x2, independent chains ----
  float s[4] = {-1e30f, -1e30f, -1e30f, -1e30f};
  const unsigned short* kbase = qkv + INNER + l * 8;
  {  // j = 0: BOS, row 0, never masked
    const u16x8 k8 = *(const u16x8*)kbase;
    float p = 0.f;
#pragma unroll
    for (int u = 0; u < 8; ++u) p = fmaf(qf[u], bf2f(k8[u]), p);
    p += __shfl_xor(p, 1); p += __shfl_xor(p, 2); p += __shfl_xor(p, 4);
    if (e == 0) s[0] = p;
  }
  {
    unsigned long long mask = mask0;
    for (int it = 0; it < nval; it += 2) {
      const int l0 = (int)__builtin_ctzll(mask);
      mask &= mask - 1;
      const bool has1 = (it + 1) < nval;
      const int l1 = mask ? (int)__builtin_ctzll(mask) : 0;
      mask &= mask - 1;                             // 0 stays 0
      const int pk0 = __shfl(my_pack, l0);          // valid by construction
      const int pk1r = __shfl(my_pack, l1);
      const int pk1 = has1 ? pk1r : 0;              // dummy row 0 on tail
      const u16x8 ka = *(const u16x8*)(kbase + (size_t)pk0 * QKV_COLS);
      const u16x8 kb = *(const u16x8*)(kbase + (size_t)pk1 * QKV_COLS);
      float p0 = 0.f, p1 = 0.f;
#pragma unroll
      for (int u = 0; u < 8; ++u) {
        p0 = fmaf(qf[u], bf2f(ka[u]), p0);
        p1 = fmaf(qf[u], bf2f(kb[u]), p1);
      }
      p0 += __shfl_xor(p0, 1); p1 += __shfl_xor(p1, 1);
      p0 += __shfl_xor(p0, 2); p1 += __shfl_xor(p1, 2);
      p0 += __shfl_xor(p0, 4); p1 += __shfl_xor(p1, 4);
      {
        const int js = l0 + 1;                      // wave-uniform
        const bool mine = (e == (js & 7));
        const int pp = js >> 3;
        s[0] = (mine && pp == 0) ? p0 : s[0];
        s[1] = (mine && pp == 1) ? p0 : s[1];
        s[2] = (mine && pp == 2) ? p0 : s[2];
        s[3] = (mine && pp == 3) ? p0 : s[3];
      }
      {
        const int js = l1 + 1;
        const bool mine = has1 && (e == (js & 7));
        const int pp = js >> 3;
        s[0] = (mine && pp == 0) ? p1 : s[0];
        s[1] = (mine && pp == 1) ? p1 : s[1];
        s[2] = (mine && pp == 2) ? p1 : s[2];
        s[3] = (mine && pp == 3) ? p1 : s[3];
      }
    }
  }

  // ---- softmax over 28 entries spread across 8 lanes x 4 regs ----
  float mx = fmaxf(fmaxf(s[0], s[1]), fmaxf(s[2], s[3]));
  mx = fmaxf(mx, __shfl_xor(mx, 1));
  mx = fmaxf(mx, __shfl_xor(mx, 2));
  mx = fmaxf(mx, __shfl_xor(mx, 4));
  float a4[4]; float sum = 0.f;
#pragma unroll
  for (int p = 0; p < 4; ++p) { a4[p] = __expf(s[p] - mx); sum += a4[p]; }
  sum += __shfl_xor(sum, 1); sum += __shfl_xor(sum, 2); sum += __shfl_xor(sum, 4);
  const float inv = 1.0f / sum;
#pragma unroll
  for (int p = 0; p < 4; ++p) a4[p] *= inv;

  // ---- talking heads: m4[p] = mixed[h][8p+e] = sum_h2 wth[h][h2]*attn[h2][8p+e] ----
  float wth[8];
  {
    const float4 w0 = *(const float4*)(w_th + gbase);
    const float4 w1 = *(const float4*)(w_th + gbase + 4);
    wth[0] = w0.x; wth[1] = w0.y; wth[2] = w0.z; wth[3] = w0.w;
    wth[4] = w1.x; wth[5] = w1.y; wth[6] = w1.z; wth[7] = w1.w;
  }
  float m4[4];
#pragma unroll
  for (int p = 0; p < 4; ++p) {
    float acc = 0.f;
#pragma unroll
    for (int h2 = 0; h2 < 8; ++h2)
      acc = fmaf(wth[h2], __shfl(a4[p], (h2 << 3) | e), acc);
    m4[p] = acc;
  }

  // ---- PV: acc8/accb dual accumulators; mask-walk unrolled x2 ----
  float acc8[8] = {0.f, 0.f, 0.f, 0.f, 0.f, 0.f, 0.f, 0.f};
  float accb[8] = {0.f, 0.f, 0.f, 0.f, 0.f, 0.f, 0.f, 0.f};
  const unsigned short* vbase = qkv + 2 * INNER + l * 8;
  {  // BOS
    const float mv = __shfl(m4[0], gbase);
    const u16x8 v8 = *(const u16x8*)vbase;
#pragma unroll
    for (int u = 0; u < 8; ++u) acc8[u] = fmaf(mv, bf2f(v8[u]), acc8[u]);
  }
  {
    unsigned long long mask = mask0;
    for (int it = 0; it < nval; it += 2) {
      const int l0 = (int)__builtin_ctzll(mask);
      mask &= mask - 1;
      const bool has1 = (it + 1) < nval;
      const int l1 = mask ? (int)__builtin_ctzll(mask) : 0;
      mask &= mask - 1;
      const int pk0 = __shfl(my_pack, l0);
      const int pk1r = __shfl(my_pack, l1);
      const int pk1 = has1 ? pk1r : 0;
      const u16x8 va = *(const u16x8*)(vbase + (size_t)pk0 * QKV_COLS);
      const u16x8 vb = *(const u16x8*)(vbase + (size_t)pk1 * QKV_COLS);
      const int js0 = l0 + 1;
      const int pp0 = js0 >> 3;
      const float ms0 = pp0 == 0 ? m4[0] : pp0 == 1 ? m4[1] : pp0 == 2 ? m4[2] : m4[3];
      const float mv0 = __shfl(ms0, gbase | (js0 & 7));
      const int js1 = l1 + 1;
      const int pp1 = js1 >> 3;
      const float ms1 = pp1 == 0 ? m4[0] : pp1 == 1 ? m4[1] : pp1 == 2 ? m4[2] : m4[3];
      const float mv1r = __shfl(ms1, gbase | (js1 & 7));
      const float mv1 = has1 ? mv1r : 0.f;          // tail contributes exactly 0
#pragma unroll
      for (int u = 0; u < 8; ++u) {
        acc8[u] = fmaf(mv0, bf2f(va[u]), acc8[u]);
        accb[u] = fmaf(mv1, bf2f(vb[u]), accb[u]);
      }
    }
  }

  // store 16B coalesced
  u16x8 o;
#pragma unroll
  for (int u = 0; u < 8; ++u) o[u] = f2bf(acc8[u] + accb[u]);
  *(u16x8*)(Ob + (size_t)(i + 1) * INNER + l * 8) = o;
}

extern "C" void kernel_launch(void* const* d_in, const int* in_sizes, int n_in,
                              void* d_out, int out_size, void* d_ws, size_t ws_size,
                              hipStream_t stream) {
  (void)in_sizes; (void)n_in; (void)out_size; (void)ws_size;
  const float* x     = (const float*)d_in[0];
  const float* w_q   = (const float*)d_in[1];
  const float* w_kv  = (const float*)d_in[2];
  const float* w_th  = (const float*)d_in[3];
  const float* w_out = (const float*)d_in[4];
  const float* b_out = (const float*)d_in[5];
  float* out = (float*)d_out;

  char* ws = (char*)d_ws;
  unsigned short* xb    = (unsigned short*)ws;                // 8448*512 bf16 (reused as Ob)
  unsigned short* wqkvT = (unsigned short*)(ws + 8650752);    // 1536*512 bf16
  unsigned short* woutT = (unsigned short*)(ws + 10223616);   // 512*512 bf16
  unsigned short* qkvb  = (unsigned short*)(ws + 10747904);   // 8193*1536 bf16

  // 1) fused conversions
  k_conv<<<CONV_TOT / 256, 256, 0, stream>>>(x, w_q, w_kv, w_out, xb, wqkvT, woutT);
  // 2) qkv = xb @ [w_q*0.125 | w_kv]   (396 blocks, 256x128 tiles, 8 waves)
  k_gemm<256, 128, QKV_COLS / 128, QKV_COLS, true>
      <<<(MPAD1 / 256) * (QKV_COLS / 128), 512, 0, stream>>>(xb, wqkvT, qkvb, nullptr, NSEQ);
  // 3) sparse attention: one wave per token, 2x2 tile per block (+1 block BOS row)
  k_attn3<<<NTOK / 4 + 1, 256, 0, stream>>>(qkvb, w_th, xb);
  // 4) out = Ob @ w_out + b_out   (520 blocks, 128x64 tiles)
  k_gemm<128, 64, DIMC / 64, DIMC, false>
      <<<(8320 / 128) * (DIMC / 64), 256, 0, stream>>>(xb, woutT, out, b_out, NSEQ);
}